// Round 6
// baseline (309.953 us; speedup 1.0000x reference)
//
#include <hip/hip_runtime.h>
#include <hip/hip_bf16.h>

#define HSEQ 16777216   // 512*32*1024
#define NH 1024

typedef __attribute__((ext_vector_type(8))) short bf16x8;
typedef __attribute__((ext_vector_type(4))) float f32x4;

__device__ __forceinline__ unsigned short f2bf(float f) {
  unsigned u = __builtin_bit_cast(unsigned, f);
  u += 0x7fffu + ((u >> 16) & 1u);
  return (unsigned short)(u >> 16);
}

__device__ __forceinline__ float fsig(float z) {   // 1/(1+e^-z)
  float e = __builtin_amdgcn_exp2f(-1.442695041f * z);
  return __builtin_amdgcn_rcpf(1.f + e);
}
__device__ __forceinline__ float ftanh(float z) {  // 1 - 2/(e^{2z}+1)
  float e = __builtin_amdgcn_exp2f(2.885390082f * z);
  return 1.f - 2.f * __builtin_amdgcn_rcpf(1.f + e);
}

// Fused fp32->bf16 conversion: x (blocks 0-2047) + 4 gate weights (blocks 2048-3071).
__global__ __launch_bounds__(256) void cvt_all(
    const float* __restrict__ x,
    const float* __restrict__ wi, const float* __restrict__ wf,
    const float* __restrict__ wo, const float* __restrict__ wg,
    unsigned short* __restrict__ xb, unsigned short* __restrict__ wb) {
  int bid = blockIdx.x;
  const float* src; unsigned short* dst; int base, iters;
  if (bid < 2048) {
    src = x; dst = xb; base = bid * 8192; iters = 8;
  } else {
    int g = bid - 2048; int ws = g >> 8; int blk = g & 255;
    src = (ws == 0) ? wi : (ws == 1) ? wf : (ws == 2) ? wo : wg;
    dst = wb + ws * 1048576; base = blk * 4096; iters = 4;
  }
  int t = threadIdx.x;
  for (int i = 0; i < iters; ++i) {
    int idx = base + i * 1024 + t * 4;
    float4 v = *reinterpret_cast<const float4*>(src + idx);
    ushort4 o;
    o.x = f2bf(v.x); o.y = f2bf(v.y); o.z = f2bf(v.z); o.w = f2bf(v.w);
    *reinterpret_cast<ushort4*>(dst + idx) = o;
  }
}

// hz[g][b][h] = h0[b,:]·w_h[g][h,:] + b_i[g][h] + b_h[g][h]
__global__ __launch_bounds__(256) void hz_kernel(
    const float* __restrict__ h0,
    const float* __restrict__ wh_i, const float* __restrict__ wh_f,
    const float* __restrict__ wh_o, const float* __restrict__ wh_g,
    const float* __restrict__ bi_i, const float* __restrict__ bh_i,
    const float* __restrict__ bi_f, const float* __restrict__ bh_f,
    const float* __restrict__ bi_o, const float* __restrict__ bh_o,
    const float* __restrict__ bi_g, const float* __restrict__ bh_g,
    float* __restrict__ hz) {
  __shared__ float ws[8 * 1024];
  int g = blockIdx.x >> 7;
  int hb = blockIdx.x & 127;
  const float* wh = (g == 0) ? wh_i : (g == 1) ? wh_f : (g == 2) ? wh_o : wh_g;
  const float* bi = (g == 0) ? bi_i : (g == 1) ? bi_f : (g == 2) ? bi_o : bi_g;
  const float* bh = (g == 0) ? bh_i : (g == 1) ? bh_f : (g == 2) ? bh_o : bh_g;
  int tid = threadIdx.x;
  const float4* wsrc = reinterpret_cast<const float4*>(wh + hb * 8 * 1024);
  float4* wdst = reinterpret_cast<float4*>(ws);
  for (int i = tid; i < 2048; i += 256) wdst[i] = wsrc[i];
  __syncthreads();
  int b = tid & 31;
  int hh = tid >> 5;
  const float4* hv = reinterpret_cast<const float4*>(h0 + b * NH);
  const float4* wv = reinterpret_cast<const float4*>(ws + hh * NH);
  float acc = 0.f;
  for (int k = 0; k < 256; ++k) {
    float4 a = hv[k], w4 = wv[k];
    acc += a.x * w4.x + a.y * w4.y + a.z * w4.z + a.w * w4.w;
  }
  int h = hb * 8 + hh;
  hz[g * (32 * NH) + b * NH + h] = acc + bi[h] + bh[h];
}

__device__ __forceinline__ void load_lds16(const void* gsrc, void* lds) {
  __builtin_amdgcn_global_load_lds(
      (const __attribute__((address_space(1))) unsigned int*)gsrc,
      (__attribute__((address_space(3))) unsigned int*)lds, 16, 0, 0);
}

// Persistent 256x256 8-phase GEMM: grid=256 (1 block/CU), each block owns
// 4 consecutive m-tiles (mg panel) x 1 ht, K-sequence of 64 tiles flows
// seamlessly across m-tile boundaries (round-5 verified schedule unchanged:
// register-double-buffered fragments, 1 stage unit/phase, VM(4)@p2/p6).
__global__ __launch_bounds__(512, 2) void lstm_gemm8(
    const unsigned short* __restrict__ xb,   // [16384][1024] bf16
    const unsigned short* __restrict__ wb,   // [4][1024][1024] bf16 (i,f,o,g)
    const float* __restrict__ hz,            // [4][32][1024] f32
    const float* __restrict__ c0,            // [32][1024] f32
    float* __restrict__ out) {
  __shared__ unsigned short As[2][16384];    // [buf][256 rows][64 cols]
  __shared__ unsigned short Bs[2][16384];

  const int bid0 = blockIdx.x;               // 256 blocks
  const int xcd = bid0 & 7;
  const int idx = bid0 >> 3;                 // 0..31
  const int mg = xcd * 2 + (idx >> 4);       // 0..15: A-panel shared within XCD
  const int ht = idx & 15;                   // 0..15
  const int hBase = ht * 64;

  const int tid = threadIdx.x;
  const int lane = tid & 63;
  const int w = tid >> 6;
  const int wr = w >> 2;        // 0..1
  const int wc = w & 3;         // 0..3
  const int laneLow = lane & 15;
  const int lane4 = lane >> 4;  // 0..3
  const int lx = lane & 7;

  const int sRow = w * 8 + (lane >> 3);               // row within 64-row round
  const int sCol = ((lane & 7) ^ (lane >> 3)) * 8;    // inverse-swizzled col
  const unsigned aRowBase = (unsigned)(mg * 1024 + sRow);
  const unsigned bOff = (unsigned)((hBase + sRow) * 1024 + sCol);

  // hoisted epilogue operands (named regs; j&2 selects)
  const int hOut = hBase + wc * 16 + laneLow;
  const int b0 = mg * 2, b1 = mg * 2 + 1;
  const float hzA0 = hz[0 * 32768 + b0 * 1024 + hOut];
  const float hzA1 = hz[1 * 32768 + b0 * 1024 + hOut];
  const float hzA2 = hz[2 * 32768 + b0 * 1024 + hOut];
  const float hzA3 = hz[3 * 32768 + b0 * 1024 + hOut];
  const float c0A  = c0[b0 * 1024 + hOut];
  const float hzB0 = hz[0 * 32768 + b1 * 1024 + hOut];
  const float hzB1 = hz[1 * 32768 + b1 * 1024 + hOut];
  const float hzB2 = hz[2 * 32768 + b1 * 1024 + hOut];
  const float hzB3 = hz[3 * 32768 + b1 * 1024 + hOut];
  const float c0B  = c0[b1 * 1024 + hOut];

#define STAGE_A(buf, t, h)                                                         \
  do {                                                                             \
    _Pragma("unroll") for (int r_ = 0; r_ < 2; ++r_) {                             \
      unsigned row_ = aRowBase + (unsigned)(((t) >> 4) * 256 + (h) * 128 + r_ * 64); \
      load_lds16(xb + (size_t)row_ * 1024 + (unsigned)(((t) & 15) * 64) + sCol,    \
                 &As[buf][(h) * 8192 + r_ * 4096 + w * 512]);                      \
    }                                                                              \
  } while (0)

#define STAGE_B(buf, t, h)                                                         \
  do {                                                                             \
    _Pragma("unroll") for (int r_ = 0; r_ < 2; ++r_) {                             \
      load_lds16(wb + (size_t)((h) * 2 + r_) * 1048576 + bOff +                    \
                     (unsigned)(((t) & 15) * 64),                                  \
                 &Bs[buf][(h) * 8192 + r_ * 4096 + w * 512]);                      \
    }                                                                              \
  } while (0)

#define LDA(dst, buf, mh)                                                          \
  do {                                                                             \
    _Pragma("unroll") for (int mi = 0; mi < 4; ++mi)                               \
    _Pragma("unroll") for (int kk = 0; kk < 2; ++kk) {                             \
      int row_ = wr * 128 + (mh) * 64 + mi * 16 + laneLow;                         \
      int slot_ = (kk * 4 + lane4) ^ lx;                                           \
      dst[mi][kk] = *reinterpret_cast<const bf16x8*>(&As[buf][row_ * 64 + slot_ * 8]); \
    }                                                                              \
  } while (0)

#define LDB(dst, buf, qh)                                                          \
  do {                                                                             \
    _Pragma("unroll") for (int q = 0; q < 2; ++q)                                  \
    _Pragma("unroll") for (int kk = 0; kk < 2; ++kk) {                             \
      int row_ = ((qh) * 2 + q) * 64 + wc * 16 + laneLow;                          \
      int slot_ = (kk * 4 + lane4) ^ lx;                                           \
      dst[q][kk] = *reinterpret_cast<const bf16x8*>(&Bs[buf][row_ * 64 + slot_ * 8]); \
    }                                                                              \
  } while (0)

#define MFMA16(A, B, MH, QH)                                                       \
  do {                                                                             \
    __builtin_amdgcn_s_setprio(1);                                                 \
    _Pragma("unroll") for (int mi = 0; mi < 4; ++mi)                               \
    _Pragma("unroll") for (int q = 0; q < 2; ++q)                                  \
    _Pragma("unroll") for (int kk = 0; kk < 2; ++kk)                               \
      acc[(MH) * 4 + mi][(QH) * 2 + q] = __builtin_amdgcn_mfma_f32_16x16x32_bf16(  \
          A[mi][kk], B[q][kk], acc[(MH) * 4 + mi][(QH) * 2 + q], 0, 0, 0);         \
    __builtin_amdgcn_s_setprio(0);                                                 \
  } while (0)

#define BAR __builtin_amdgcn_s_barrier()
#define VM(n) asm volatile("s_waitcnt vmcnt(" #n ")" ::: "memory")

  f32x4 acc[8][4];
#pragma unroll
  for (int i = 0; i < 8; ++i)
#pragma unroll
    for (int jj = 0; jj < 4; ++jj) acc[i][jj] = (f32x4){0.f, 0.f, 0.f, 0.f};

  bf16x8 afX[4][2], afY[4][2], bqA[2][2], bqB[2][2];

  // Prologue: buf0 <- tile0 complete; buf1 <- tile1 (B0,B1,A0).
  STAGE_B(0, 0, 0); STAGE_B(0, 0, 1); STAGE_A(0, 0, 0); STAGE_A(0, 0, 1);
  STAGE_B(1, 1, 0); STAGE_B(1, 1, 1); STAGE_A(1, 1, 0);
  VM(0);
  BAR;
  LDB(bqA, 0, 0);
  LDA(afX, 0, 0);

  for (int j = 0; j < 4; ++j) {        // m-tile loop (dynamic)
#pragma unroll
    for (int it2 = 0; it2 < 8; ++it2) {
      const int itg = j * 8 + it2;
      const int tOdd = 2 * itg + 1;
      const int tA2 = (2 * itg + 2 > 63) ? 63 : 2 * itg + 2;
      const int tB2 = (2 * itg + 3 > 63) ? 63 : 2 * itg + 3;

      // p0
      LDB(bqB, 0, 1);
      STAGE_A(1, tOdd, 1);
      MFMA16(afX, bqA, 0, 0);
      BAR;
      // p1
      LDA(afY, 0, 1);
      STAGE_B(0, tA2, 0);
      MFMA16(afX, bqB, 0, 1);
      BAR;
      // p2
      STAGE_B(0, tA2, 1);
      MFMA16(afY, bqB, 1, 1);
      VM(4);
      BAR;
      // p3
      LDB(bqB, 1, 0);
      LDA(afX, 1, 0);
      STAGE_A(0, tA2, 0);
      MFMA16(afY, bqA, 1, 0);
      BAR;
      // p4
      LDB(bqA, 1, 1);
      STAGE_A(0, tA2, 1);
      MFMA16(afX, bqB, 0, 0);
      BAR;
      // p5
      LDA(afY, 1, 1);
      STAGE_B(1, tB2, 0);
      MFMA16(afX, bqA, 0, 1);
      BAR;
      // p6
      STAGE_B(1, tB2, 1);
      MFMA16(afY, bqA, 1, 1);
      VM(4);
      BAR;
      // p7
      LDB(bqA, 0, 0);
      LDA(afX, 0, 0);
      STAGE_A(1, tB2, 0);
      MFMA16(afY, bqB, 1, 0);
      BAR;
    }

    // ---- epilogue for m-tile j (register-only math + stores; no barrier) ----
    {
      const int mB = mg * 1024 + j * 256;
      const bool hi = (j & 2) != 0;
      const float hz0 = hi ? hzB0 : hzA0;
      const float hz1 = hi ? hzB1 : hzA1;
      const float hz2 = hi ? hzB2 : hzA2;
      const float hz3 = hi ? hzB3 : hzA3;
      const float c0v = hi ? c0B : c0A;
      const int b = mB >> 9;
#pragma unroll
      for (int mi16 = 0; mi16 < 8; ++mi16) {
#pragma unroll
        for (int r = 0; r < 4; ++r) {
          int m = mB + wr * 128 + mi16 * 16 + lane4 * 4 + r;
          int ts = m & 511;
          float zi = acc[mi16][0][r] + hz0;
          float zf = acc[mi16][1][r] + hz1;
          float zo = acc[mi16][2][r] + hz2;
          float zg = acc[mi16][3][r] + hz3;
          float iv = fsig(zi);
          float fv = fsig(zf);
          float ov = fsig(zo);
          float gv = ftanh(zg);
          float cv = fv * c0v + iv * gv;
          float hval = ov * ftanh(cv);
          out[(size_t)ts * 32768 + b * 1024 + hOut] = hval;
          if (ts == 511) {
            out[HSEQ + b * 1024 + hOut] = hval;
            out[HSEQ + 32768 + b * 1024 + hOut] = cv;
          }
        }
      }
#pragma unroll
      for (int i = 0; i < 8; ++i)
#pragma unroll
        for (int jj = 0; jj < 4; ++jj) acc[i][jj] = (f32x4){0.f, 0.f, 0.f, 0.f};
    }
  }
}

extern "C" void kernel_launch(void* const* d_in, const int* in_sizes, int n_in,
                              void* d_out, int out_size, void* d_ws, size_t ws_size,
                              hipStream_t stream) {
  const float* x    = (const float*)d_in[0];
  const float* h0   = (const float*)d_in[1];
  const float* c0   = (const float*)d_in[2];
  const float* w_ii = (const float*)d_in[3];
  const float* b_ii = (const float*)d_in[4];
  const float* w_hi = (const float*)d_in[5];
  const float* b_hi = (const float*)d_in[6];
  const float* w_if = (const float*)d_in[7];
  const float* b_if = (const float*)d_in[8];
  const float* w_hf = (const float*)d_in[9];
  const float* b_hf = (const float*)d_in[10];
  const float* w_io = (const float*)d_in[11];
  const float* b_io = (const float*)d_in[12];
  const float* w_ho = (const float*)d_in[13];
  const float* b_ho = (const float*)d_in[14];
  const float* w_ig = (const float*)d_in[15];
  const float* b_ig = (const float*)d_in[16];
  const float* w_hg = (const float*)d_in[17];
  const float* b_hg = (const float*)d_in[18];

  unsigned short* xb = (unsigned short*)d_ws;          // 16777216 bf16
  unsigned short* wb = xb + 16777216;                  // 4*1048576 bf16
  float* hz = (float*)(wb + 4 * 1048576);              // 4*32*1024 f32
  float* out = (float*)d_out;

  hipLaunchKernelGGL(cvt_all, dim3(3072), dim3(256), 0, stream,
                     x, w_ii, w_if, w_io, w_ig, xb, wb);
  hipLaunchKernelGGL(hz_kernel, dim3(512), dim3(256), 0, stream, h0,
                     w_hi, w_hf, w_ho, w_hg,
                     b_ii, b_hi, b_if, b_hf, b_io, b_ho, b_ig, b_hg, hz);
  hipLaunchKernelGGL(lstm_gemm8, dim3(256), dim3(512), 0, stream, xb, wb, hz, c0, out);
}